// Round 5
// baseline (474.380 us; speedup 1.0000x reference)
//
#include <hip/hip_runtime.h>

// Fully-fused CIN: one block per batch row b runs all 3 layers + score.
//   Y_hh[o,d] = sum_m W[o,hh,m] * x0[b,m,d]      (MFMA, 3-term bf16 split)
//   h_next[o,d] = relu(bias[o] + sum_hh h[hh,d] * Y_hh[o,d])   (VALU, fp32)
// h ping-pongs in LDS (32KB each); score accumulated in-block; only W/x0
// fragment planes are read from global (L2/L3-hot), 4-deep prefetched.
// B=512, M=32, D=64, O=128/layer, H = 32/128/128.

constexpr int Bb = 512, Mm = 32, Dd = 64, Oo = 128;

typedef __attribute__((ext_vector_type(8))) short bf16x8;
typedef __attribute__((ext_vector_type(4))) float f32x4;

static __device__ __forceinline__ ushort f2bf(float f) {
  union { float f; uint u; } v;
  v.f = f;
  uint u = v.u;
  return (ushort)((u + 0x7FFFu + ((u >> 16) & 1u)) >> 16);  // RNE
}
static __device__ __forceinline__ float bf2f(ushort b) {
  union { uint u; float f; } v;
  v.u = (uint)b << 16;
  return v.f;
}

// W[o][hh*32+m] -> A-frag planes [hh][f][lane][j]: o=f*16+(lane&15), m=(lane>>4)*8+j
static __device__ __forceinline__ void wsplit_one(const float* __restrict__ W,
                                                  ushort* __restrict__ Whi,
                                                  ushort* __restrict__ Wlo,
                                                  int H, int t) {
  int l = t & 63, fo = (t >> 6) & 7, hh = t >> 9;
  int o = fo * 16 + (l & 15);
  int m0 = (l >> 4) * 8;
  const float* src = W + (size_t)o * (H * 32) + hh * 32 + m0;
  ushort hi[8], lo[8];
#pragma unroll
  for (int j = 0; j < 8; ++j) {
    float w = src[j];
    ushort h = f2bf(w);
    hi[j] = h;
    lo[j] = f2bf(w - bf2f(h));
  }
  *reinterpret_cast<uint4*>(Whi + (size_t)t * 8) = *reinterpret_cast<uint4*>(hi);
  *reinterpret_cast<uint4*>(Wlo + (size_t)t * 8) = *reinterpret_cast<uint4*>(lo);
}

// x0[b][m][d] -> B-frag planes [b][fd][lane][j]: m=(lane>>4)*8+j, d=fd*16+(lane&15)
static __device__ __forceinline__ void x0split_one(const float* __restrict__ x0,
                                                   ushort* __restrict__ Xhi,
                                                   ushort* __restrict__ Xlo, int t) {
  int l = t & 63, fd = (t >> 6) & 3, b = t >> 8;
  int d = fd * 16 + (l & 15);
  int m0 = (l >> 4) * 8;
  const float* src = x0 + ((size_t)b * Mm + m0) * Dd + d;
  ushort hi[8], lo[8];
#pragma unroll
  for (int j = 0; j < 8; ++j) {
    float w = src[j * Dd];
    ushort h = f2bf(w);
    hi[j] = h;
    lo[j] = f2bf(w - bf2f(h));
  }
  *reinterpret_cast<uint4*>(Xhi + (size_t)t * 8) = *reinterpret_cast<uint4*>(hi);
  *reinterpret_cast<uint4*>(Xlo + (size_t)t * 8) = *reinterpret_cast<uint4*>(lo);
}

__global__ __launch_bounds__(256) void prep_kernel(
    const float* __restrict__ W0, const float* __restrict__ W1,
    const float* __restrict__ W2, const float* __restrict__ x0,
    ushort* __restrict__ Whi0, ushort* __restrict__ Wlo0,
    ushort* __restrict__ Whi1, ushort* __restrict__ Wlo1,
    ushort* __restrict__ Whi2, ushort* __restrict__ Wlo2,
    ushort* __restrict__ Xhi, ushort* __restrict__ Xlo) {
  int t = blockIdx.x * 256 + threadIdx.x;
  if (t < 16384) {
    wsplit_one(W0, Whi0, Wlo0, 32, t);
  } else if (t < 81920) {
    wsplit_one(W1, Whi1, Wlo1, 128, t - 16384);
  } else if (t < 147456) {
    wsplit_one(W2, Whi2, Wlo2, 128, t - 81920);
  } else {
    x0split_one(x0, Xhi, Xlo, t - 147456);
  }
}

// One layer for one wave: o-tile = f*16..f*16+15, all d. Reads h from LDS,
// writes relu output to LDS (unless !WRITE_H), accumulates score_part.
template <int H, bool WRITE_H>
static __device__ __forceinline__ void run_layer(
    const float* __restrict__ h_lds,   // [H*64] (LDS)
    float* __restrict__ h_next,        // [128*64] (LDS)
    const ushort* __restrict__ Whi, const ushort* __restrict__ Wlo,
    const float* __restrict__ bias, const float* __restrict__ lw,
    const bf16x8 (&xh)[4], const bf16x8 (&xl)[4],
    int f, int lane, float& score_part) {
  const int cid = lane & 15;
  const size_t hstride = (size_t)8 * 64 * 8;  // ushorts per hh
  const ushort* pwh = Whi + ((size_t)f * 64 + lane) * 8;
  const ushort* pwl = Wlo + ((size_t)f * 64 + lane) * 8;

  const f32x4 kZ = {0.f, 0.f, 0.f, 0.f};
  f32x4 acc[4];
#pragma unroll
  for (int fd = 0; fd < 4; ++fd) acc[fd] = kZ;

  // 4-deep A-fragment prefetch; 1-ahead h prefetch (LDS, ~120cyc < step time)
  bf16x8 Ah[4], Al[4];
#pragma unroll
  for (int j = 0; j < 4; ++j) {
    Ah[j] = *reinterpret_cast<const bf16x8*>(pwh + (size_t)j * hstride);
    Al[j] = *reinterpret_cast<const bf16x8*>(pwl + (size_t)j * hstride);
  }
  float hvc[4];
#pragma unroll
  for (int fd = 0; fd < 4; ++fd) hvc[fd] = h_lds[fd * 16 + cid];

#pragma unroll 1
  for (int hh4 = 0; hh4 < H; hh4 += 4) {
#pragma unroll
    for (int j = 0; j < 4; ++j) {
      const int hh = hh4 + j;
      // h for hh+1 (clamped)
      const int hn1 = (hh + 1 < H) ? hh + 1 : H - 1;
      float nhv[4];
#pragma unroll
      for (int fd = 0; fd < 4; ++fd) nhv[fd] = h_lds[hn1 * 64 + fd * 16 + cid];

      f32x4 y[4];
#pragma unroll
      for (int fd = 0; fd < 4; ++fd)
        y[fd] = __builtin_amdgcn_mfma_f32_16x16x32_bf16(Ah[j], xh[fd], kZ, 0, 0, 0);
#pragma unroll
      for (int fd = 0; fd < 4; ++fd)
        y[fd] = __builtin_amdgcn_mfma_f32_16x16x32_bf16(Ah[j], xl[fd], y[fd], 0, 0, 0);
#pragma unroll
      for (int fd = 0; fd < 4; ++fd)
        y[fd] = __builtin_amdgcn_mfma_f32_16x16x32_bf16(Al[j], xh[fd], y[fd], 0, 0, 0);

      // refill slot j with hh+4 (clamped) while MFMAs drain
      const int hn4 = (hh + 4 < H) ? hh + 4 : H - 1;
      Ah[j] = *reinterpret_cast<const bf16x8*>(pwh + (size_t)hn4 * hstride);
      Al[j] = *reinterpret_cast<const bf16x8*>(pwl + (size_t)hn4 * hstride);

#pragma unroll
      for (int fd = 0; fd < 4; ++fd)
#pragma unroll
        for (int r = 0; r < 4; ++r)
          acc[fd][r] = fmaf(hvc[fd], y[fd][r], acc[fd][r]);
#pragma unroll
      for (int fd = 0; fd < 4; ++fd) hvc[fd] = nhv[fd];
    }
  }

  // epilogue: bias + relu, write h_next (LDS), fold d-sum into score
  const int rg = lane >> 4;
#pragma unroll
  for (int r = 0; r < 4; ++r) {
    const int o = f * 16 + rg * 4 + r;
    const float bs = bias[o];
    float sd = 0.f;
#pragma unroll
    for (int fd = 0; fd < 4; ++fd) {
      float v = acc[fd][r] + bs;
      v = v > 0.f ? v : 0.f;
      if (WRITE_H) h_next[o * 64 + fd * 16 + cid] = v;
      sd += v;
    }
#pragma unroll
    for (int mk = 1; mk < 16; mk <<= 1) sd += __shfl_xor(sd, mk, 64);
    if (cid == 0) score_part = fmaf(sd, lw[o], score_part);
  }
}

__global__ __launch_bounds__(512, 4) void cin_fused_kernel(
    const float* __restrict__ x0,
    const ushort* __restrict__ Whi0, const ushort* __restrict__ Wlo0,
    const ushort* __restrict__ Whi1, const ushort* __restrict__ Wlo1,
    const ushort* __restrict__ Whi2, const ushort* __restrict__ Wlo2,
    const ushort* __restrict__ Xhi, const ushort* __restrict__ Xlo,
    const float* __restrict__ b0, const float* __restrict__ b1,
    const float* __restrict__ b2, const float* __restrict__ lw,
    const float* __restrict__ lb, float* __restrict__ out) {
  __shared__ float hA[Oo * Dd];  // 32KB: x0 (layer0 in), then layer1 out
  __shared__ float hB[Oo * Dd];  // 32KB: layer0 out
  __shared__ float sred[8];

  const int b = blockIdx.x;
  const int t = threadIdx.x;
  const int lane = t & 63;
  const int f = __builtin_amdgcn_readfirstlane(t >> 6);  // wave id = o-tile

  // stage x0[b] (32x64 f32 = 8KB) into hA
  reinterpret_cast<float4*>(hA)[t] =
      reinterpret_cast<const float4*>(x0 + (size_t)b * Mm * Dd)[t];

  // x0 B-fragments, register-resident throughout
  bf16x8 xh[4], xl[4];
#pragma unroll
  for (int fd = 0; fd < 4; ++fd) {
    size_t off = (((size_t)b * 4 + fd) * 64 + lane) * 8;
    xh[fd] = *reinterpret_cast<const bf16x8*>(Xhi + off);
    xl[fd] = *reinterpret_cast<const bf16x8*>(Xlo + off);
  }

  __syncthreads();

  float score_part = 0.f;
  run_layer<32, true>(hA, hB, Whi0, Wlo0, b0, lw, xh, xl, f, lane, score_part);
  __syncthreads();
  run_layer<128, true>(hB, hA, Whi1, Wlo1, b1, lw + 128, xh, xl, f, lane, score_part);
  __syncthreads();
  run_layer<128, false>(hA, hB, Whi2, Wlo2, b2, lw + 256, xh, xl, f, lane, score_part);

  // block-wide score reduction
#pragma unroll
  for (int mk = 1; mk < 64; mk <<= 1) score_part += __shfl_xor(score_part, mk, 64);
  if (lane == 0) sred[f] = score_part;
  __syncthreads();
  if (t == 0) {
    float tot = 0.f;
#pragma unroll
    for (int i = 0; i < 8; ++i) tot += sred[i];
    out[b] = tot + lb[0];
  }
}

extern "C" void kernel_launch(void* const* d_in, const int* in_sizes, int n_in,
                              void* d_out, int out_size, void* d_ws, size_t ws_size,
                              hipStream_t stream) {
  const float* x0 = (const float*)d_in[0];
  const float* W0 = (const float*)d_in[1];
  const float* b0 = (const float*)d_in[2];
  const float* W1 = (const float*)d_in[3];
  const float* b1 = (const float*)d_in[4];
  const float* W2 = (const float*)d_in[5];
  const float* b2 = (const float*)d_in[6];
  const float* lw = (const float*)d_in[7];
  const float* lb = (const float*)d_in[8];
  float* out = (float*)d_out;

  // workspace: only the split planes
  ushort* Whi0 = (ushort*)d_ws;
  ushort* Wlo0 = Whi0 + (size_t)32 * 8 * 64 * 8;
  ushort* Whi1 = Wlo0 + (size_t)32 * 8 * 64 * 8;
  ushort* Wlo1 = Whi1 + (size_t)128 * 8 * 64 * 8;
  ushort* Whi2 = Wlo1 + (size_t)128 * 8 * 64 * 8;
  ushort* Wlo2 = Whi2 + (size_t)128 * 8 * 64 * 8;
  ushort* Xhi = Wlo2 + (size_t)128 * 8 * 64 * 8;
  ushort* Xlo = Xhi + (size_t)Bb * 4 * 64 * 8;

  prep_kernel<<<dim3(1088), dim3(256), 0, stream>>>(W0, W1, W2, x0, Whi0, Wlo0,
                                                    Whi1, Wlo1, Whi2, Wlo2, Xhi, Xlo);

  cin_fused_kernel<<<dim3(Bb), dim3(512), 0, stream>>>(
      x0, Whi0, Wlo0, Whi1, Wlo1, Whi2, Wlo2, Xhi, Xlo, b0, b1, b2, lw, lb, out);
}

// Round 6
// 251.369 us; speedup vs baseline: 1.8872x; 1.8872x over previous
//
#include <hip/hip_runtime.h>

// Fully-fused CIN: one block per batch row b runs all 3 layers + score.
//   Y_hh[o,d] = sum_m W[o,hh,m] * x0[b,m,d]      (MFMA, 3-term bf16 split)
//   h_next[o,d] = relu(bias[o] + sum_hh h[hh,d] * Y_hh[o,d])   (VALU, fp32)
// h ping-pongs in LDS; score accumulated in-block. W/x0 fragment planes are
// read from global (L2/L3-hot), A-frags 3-deep register-prefetched.
// Round-5 fix: __launch_bounds__(512,2) -> 128-VGPR budget (the (512,4) of
// round 4 was interpreted as 4 blocks/CU -> 64-VGPR cap -> 560MB of spills).
// B=512, M=32, D=64, O=128/layer, H = 32/128/128.

constexpr int Bb = 512, Mm = 32, Dd = 64, Oo = 128;

typedef __attribute__((ext_vector_type(8))) short bf16x8;
typedef __attribute__((ext_vector_type(4))) float f32x4;

static __device__ __forceinline__ ushort f2bf(float f) {
  union { float f; uint u; } v;
  v.f = f;
  uint u = v.u;
  return (ushort)((u + 0x7FFFu + ((u >> 16) & 1u)) >> 16);  // RNE
}
static __device__ __forceinline__ float bf2f(ushort b) {
  union { uint u; float f; } v;
  v.u = (uint)b << 16;
  return v.f;
}

// W[o][hh*32+m] -> A-frag planes [hh][f][lane][j]: o=f*16+(lane&15), m=(lane>>4)*8+j
static __device__ __forceinline__ void wsplit_one(const float* __restrict__ W,
                                                  ushort* __restrict__ Whi,
                                                  ushort* __restrict__ Wlo,
                                                  int H, int t) {
  int l = t & 63, fo = (t >> 6) & 7, hh = t >> 9;
  int o = fo * 16 + (l & 15);
  int m0 = (l >> 4) * 8;
  const float* src = W + (size_t)o * (H * 32) + hh * 32 + m0;
  ushort hi[8], lo[8];
#pragma unroll
  for (int j = 0; j < 8; ++j) {
    float w = src[j];
    ushort h = f2bf(w);
    hi[j] = h;
    lo[j] = f2bf(w - bf2f(h));
  }
  *reinterpret_cast<uint4*>(Whi + (size_t)t * 8) = *reinterpret_cast<uint4*>(hi);
  *reinterpret_cast<uint4*>(Wlo + (size_t)t * 8) = *reinterpret_cast<uint4*>(lo);
}

// x0[b][m][d] -> B-frag planes [b][fd][lane][j]: m=(lane>>4)*8+j, d=fd*16+(lane&15)
static __device__ __forceinline__ void x0split_one(const float* __restrict__ x0,
                                                   ushort* __restrict__ Xhi,
                                                   ushort* __restrict__ Xlo, int t) {
  int l = t & 63, fd = (t >> 6) & 3, b = t >> 8;
  int d = fd * 16 + (l & 15);
  int m0 = (l >> 4) * 8;
  const float* src = x0 + ((size_t)b * Mm + m0) * Dd + d;
  ushort hi[8], lo[8];
#pragma unroll
  for (int j = 0; j < 8; ++j) {
    float w = src[j * Dd];
    ushort h = f2bf(w);
    hi[j] = h;
    lo[j] = f2bf(w - bf2f(h));
  }
  *reinterpret_cast<uint4*>(Xhi + (size_t)t * 8) = *reinterpret_cast<uint4*>(hi);
  *reinterpret_cast<uint4*>(Xlo + (size_t)t * 8) = *reinterpret_cast<uint4*>(lo);
}

__global__ __launch_bounds__(256) void prep_kernel(
    const float* __restrict__ W0, const float* __restrict__ W1,
    const float* __restrict__ W2, const float* __restrict__ x0,
    ushort* __restrict__ Whi0, ushort* __restrict__ Wlo0,
    ushort* __restrict__ Whi1, ushort* __restrict__ Wlo1,
    ushort* __restrict__ Whi2, ushort* __restrict__ Wlo2,
    ushort* __restrict__ Xhi, ushort* __restrict__ Xlo) {
  int t = blockIdx.x * 256 + threadIdx.x;
  if (t < 16384) {
    wsplit_one(W0, Whi0, Wlo0, 32, t);
  } else if (t < 81920) {
    wsplit_one(W1, Whi1, Wlo1, 128, t - 16384);
  } else if (t < 147456) {
    wsplit_one(W2, Whi2, Wlo2, 128, t - 81920);
  } else {
    x0split_one(x0, Xhi, Xlo, t - 147456);
  }
}

// One layer for one wave: o-tile = f*16..f*16+15, all d. Reads h from LDS,
// writes relu output to LDS (unless !WRITE_H), accumulates score_part.
template <int H, bool WRITE_H>
static __device__ __forceinline__ void run_layer(
    const float* __restrict__ h_lds,   // [H*64] (LDS)
    float* __restrict__ h_next,        // [128*64] (LDS)
    const ushort* __restrict__ Whi, const ushort* __restrict__ Wlo,
    const float* __restrict__ bias, const float* __restrict__ lw,
    const bf16x8 (&xh)[4], const bf16x8 (&xl)[4],
    int f, int lane, float& score_part) {
  const int cid = lane & 15;
  const size_t hstride = (size_t)8 * 64 * 8;  // ushorts per hh
  const ushort* pwh = Whi + ((size_t)f * 64 + lane) * 8;
  const ushort* pwl = Wlo + ((size_t)f * 64 + lane) * 8;

  const f32x4 kZ = {0.f, 0.f, 0.f, 0.f};
  f32x4 acc[4];
#pragma unroll
  for (int fd = 0; fd < 4; ++fd) acc[fd] = kZ;

  // 3-deep A-fragment prefetch ring; 1-ahead h prefetch (LDS)
  bf16x8 Ah[3], Al[3];
#pragma unroll
  for (int j = 0; j < 3; ++j) {
    Ah[j] = *reinterpret_cast<const bf16x8*>(pwh + (size_t)j * hstride);
    Al[j] = *reinterpret_cast<const bf16x8*>(pwl + (size_t)j * hstride);
  }
  float hvc[4];
#pragma unroll
  for (int fd = 0; fd < 4; ++fd) hvc[fd] = h_lds[fd * 16 + cid];

#pragma unroll 1
  for (int hh3 = 0; hh3 < H; hh3 += 3) {  // H % 3 != 0: tail handled by clamp
#pragma unroll
    for (int j = 0; j < 3; ++j) {
      const int hh = hh3 + j;
      if (H % 3 != 0 && hh >= H) break;
      // h for hh+1 (clamped)
      const int hn1 = (hh + 1 < H) ? hh + 1 : H - 1;
      float nhv[4];
#pragma unroll
      for (int fd = 0; fd < 4; ++fd) nhv[fd] = h_lds[hn1 * 64 + fd * 16 + cid];

      f32x4 y[4];
#pragma unroll
      for (int fd = 0; fd < 4; ++fd)
        y[fd] = __builtin_amdgcn_mfma_f32_16x16x32_bf16(Ah[j], xh[fd], kZ, 0, 0, 0);
#pragma unroll
      for (int fd = 0; fd < 4; ++fd)
        y[fd] = __builtin_amdgcn_mfma_f32_16x16x32_bf16(Ah[j], xl[fd], y[fd], 0, 0, 0);
#pragma unroll
      for (int fd = 0; fd < 4; ++fd)
        y[fd] = __builtin_amdgcn_mfma_f32_16x16x32_bf16(Al[j], xh[fd], y[fd], 0, 0, 0);

      // refill slot j with hh+3 (clamped) while MFMAs drain
      const int hn3 = (hh + 3 < H) ? hh + 3 : H - 1;
      Ah[j] = *reinterpret_cast<const bf16x8*>(pwh + (size_t)hn3 * hstride);
      Al[j] = *reinterpret_cast<const bf16x8*>(pwl + (size_t)hn3 * hstride);

#pragma unroll
      for (int fd = 0; fd < 4; ++fd)
#pragma unroll
        for (int r = 0; r < 4; ++r)
          acc[fd][r] = fmaf(hvc[fd], y[fd][r], acc[fd][r]);
#pragma unroll
      for (int fd = 0; fd < 4; ++fd) hvc[fd] = nhv[fd];
    }
  }

  // epilogue: bias + relu, write h_next (LDS), fold d-sum into score
  const int rg = lane >> 4;
#pragma unroll
  for (int r = 0; r < 4; ++r) {
    const int o = f * 16 + rg * 4 + r;
    const float bs = bias[o];
    float sd = 0.f;
#pragma unroll
    for (int fd = 0; fd < 4; ++fd) {
      float v = acc[fd][r] + bs;
      v = v > 0.f ? v : 0.f;
      if (WRITE_H) h_next[o * 64 + fd * 16 + cid] = v;
      sd += v;
    }
#pragma unroll
    for (int mk = 1; mk < 16; mk <<= 1) sd += __shfl_xor(sd, mk, 64);
    if (cid == 0) score_part = fmaf(sd, lw[o], score_part);
  }
}

__global__ __launch_bounds__(512, 2) void cin_fused_kernel(
    const float* __restrict__ x0,
    const ushort* __restrict__ Whi0, const ushort* __restrict__ Wlo0,
    const ushort* __restrict__ Whi1, const ushort* __restrict__ Wlo1,
    const ushort* __restrict__ Whi2, const ushort* __restrict__ Wlo2,
    const ushort* __restrict__ Xhi, const ushort* __restrict__ Xlo,
    const float* __restrict__ b0, const float* __restrict__ b1,
    const float* __restrict__ b2, const float* __restrict__ lw,
    const float* __restrict__ lb, float* __restrict__ out) {
  __shared__ float hA[Oo * Dd];  // 32KB: x0 (layer0 in), then layer1 out
  __shared__ float hB[Oo * Dd];  // 32KB: layer0 out
  __shared__ float sred[8];

  const int b = blockIdx.x;
  const int t = threadIdx.x;
  const int lane = t & 63;
  const int f = __builtin_amdgcn_readfirstlane(t >> 6);  // wave id = o-tile

  // stage x0[b] (32x64 f32 = 8KB) into hA
  reinterpret_cast<float4*>(hA)[t] =
      reinterpret_cast<const float4*>(x0 + (size_t)b * Mm * Dd)[t];

  // x0 B-fragments, register-resident throughout
  bf16x8 xh[4], xl[4];
#pragma unroll
  for (int fd = 0; fd < 4; ++fd) {
    size_t off = (((size_t)b * 4 + fd) * 64 + lane) * 8;
    xh[fd] = *reinterpret_cast<const bf16x8*>(Xhi + off);
    xl[fd] = *reinterpret_cast<const bf16x8*>(Xlo + off);
  }

  __syncthreads();

  float score_part = 0.f;
  run_layer<32, true>(hA, hB, Whi0, Wlo0, b0, lw, xh, xl, f, lane, score_part);
  __syncthreads();
  run_layer<128, true>(hB, hA, Whi1, Wlo1, b1, lw + 128, xh, xl, f, lane, score_part);
  __syncthreads();
  run_layer<128, false>(hA, hB, Whi2, Wlo2, b2, lw + 256, xh, xl, f, lane, score_part);

  // block-wide score reduction
#pragma unroll
  for (int mk = 1; mk < 64; mk <<= 1) score_part += __shfl_xor(score_part, mk, 64);
  if (lane == 0) sred[f] = score_part;
  __syncthreads();
  if (t == 0) {
    float tot = 0.f;
#pragma unroll
    for (int i = 0; i < 8; ++i) tot += sred[i];
    out[b] = tot + lb[0];
  }
}

extern "C" void kernel_launch(void* const* d_in, const int* in_sizes, int n_in,
                              void* d_out, int out_size, void* d_ws, size_t ws_size,
                              hipStream_t stream) {
  const float* x0 = (const float*)d_in[0];
  const float* W0 = (const float*)d_in[1];
  const float* b0 = (const float*)d_in[2];
  const float* W1 = (const float*)d_in[3];
  const float* b1 = (const float*)d_in[4];
  const float* W2 = (const float*)d_in[5];
  const float* b2 = (const float*)d_in[6];
  const float* lw = (const float*)d_in[7];
  const float* lb = (const float*)d_in[8];
  float* out = (float*)d_out;

  // workspace: only the split planes
  ushort* Whi0 = (ushort*)d_ws;
  ushort* Wlo0 = Whi0 + (size_t)32 * 8 * 64 * 8;
  ushort* Whi1 = Wlo0 + (size_t)32 * 8 * 64 * 8;
  ushort* Wlo1 = Whi1 + (size_t)128 * 8 * 64 * 8;
  ushort* Whi2 = Wlo1 + (size_t)128 * 8 * 64 * 8;
  ushort* Wlo2 = Whi2 + (size_t)128 * 8 * 64 * 8;
  ushort* Xhi = Wlo2 + (size_t)128 * 8 * 64 * 8;
  ushort* Xlo = Xhi + (size_t)Bb * 4 * 64 * 8;

  prep_kernel<<<dim3(1088), dim3(256), 0, stream>>>(W0, W1, W2, x0, Whi0, Wlo0,
                                                    Whi1, Wlo1, Whi2, Wlo2, Xhi, Xlo);

  cin_fused_kernel<<<dim3(Bb), dim3(512), 0, stream>>>(
      x0, Whi0, Wlo0, Whi1, Wlo1, Whi2, Wlo2, Xhi, Xlo, b0, b1, b2, lw, lb, out);
}

// Round 9
// 247.797 us; speedup vs baseline: 1.9144x; 1.0144x over previous
//
#include <hip/hip_runtime.h>

// Fully-fused CIN (16x16x32 MFMA — layouts HW-verified by rounds 2-5).
//   Y_hh[o,d] = sum_m W[o,hh,m] * x0[b,m,d]      (MFMA, 3-term bf16 split)
//   h_next[o,d] = relu(bias[o] + sum_hh h[hh,d] * Y_hh[o,d])   (VALU, fp32)
// One block per b, 8 waves (one o-frag each). h ping-pongs in LDS.
// Round-8 fix vs round 5: LDS shrunk 66048 -> exactly 65536 B (x0 read from
// global for layer 0's hv; score-reduction scratch folded into dead hB) so
// TWO blocks fit the 128 KiB schedulable LDS pool -> 4 waves/SIMD.
// B=512, M=32, D=64, O=128/layer, H = 32/128/128.

constexpr int Bb = 512, Mm = 32, Dd = 64, Oo = 128;

typedef __attribute__((ext_vector_type(8))) short bf16x8;
typedef __attribute__((ext_vector_type(4))) float f32x4;

static __device__ __forceinline__ ushort f2bf(float f) {
  union { float f; uint u; } v;
  v.f = f;
  uint u = v.u;
  return (ushort)((u + 0x7FFFu + ((u >> 16) & 1u)) >> 16);  // RNE
}
static __device__ __forceinline__ float bf2f(ushort b) {
  union { uint u; float f; } v;
  v.u = (uint)b << 16;
  return v.f;
}

// W[o][hh*32+m] -> A-frag planes [hh][f][lane][j]: o=f*16+(lane&15), m=(lane>>4)*8+j
static __device__ __forceinline__ void wsplit_one(const float* __restrict__ W,
                                                  ushort* __restrict__ Whi,
                                                  ushort* __restrict__ Wlo,
                                                  int H, int t) {
  int l = t & 63, fo = (t >> 6) & 7, hh = t >> 9;
  int o = fo * 16 + (l & 15);
  int m0 = (l >> 4) * 8;
  const float* src = W + (size_t)o * (H * 32) + hh * 32 + m0;
  ushort hi[8], lo[8];
#pragma unroll
  for (int j = 0; j < 8; ++j) {
    float w = src[j];
    ushort h = f2bf(w);
    hi[j] = h;
    lo[j] = f2bf(w - bf2f(h));
  }
  *reinterpret_cast<uint4*>(Whi + (size_t)t * 8) = *reinterpret_cast<uint4*>(hi);
  *reinterpret_cast<uint4*>(Wlo + (size_t)t * 8) = *reinterpret_cast<uint4*>(lo);
}

// x0[b][m][d] -> B-frag planes [b][fd][lane][j]: m=(lane>>4)*8+j, d=fd*16+(lane&15)
static __device__ __forceinline__ void x0split_one(const float* __restrict__ x0,
                                                   ushort* __restrict__ Xhi,
                                                   ushort* __restrict__ Xlo, int t) {
  int l = t & 63, fd = (t >> 6) & 3, b = t >> 8;
  int d = fd * 16 + (l & 15);
  int m0 = (l >> 4) * 8;
  const float* src = x0 + ((size_t)b * Mm + m0) * Dd + d;
  ushort hi[8], lo[8];
#pragma unroll
  for (int j = 0; j < 8; ++j) {
    float w = src[j * Dd];
    ushort h = f2bf(w);
    hi[j] = h;
    lo[j] = f2bf(w - bf2f(h));
  }
  *reinterpret_cast<uint4*>(Xhi + (size_t)t * 8) = *reinterpret_cast<uint4*>(hi);
  *reinterpret_cast<uint4*>(Xlo + (size_t)t * 8) = *reinterpret_cast<uint4*>(lo);
}

__global__ __launch_bounds__(256) void prep_kernel(
    const float* __restrict__ W0, const float* __restrict__ W1,
    const float* __restrict__ W2, const float* __restrict__ x0,
    ushort* __restrict__ Whi0, ushort* __restrict__ Wlo0,
    ushort* __restrict__ Whi1, ushort* __restrict__ Wlo1,
    ushort* __restrict__ Whi2, ushort* __restrict__ Wlo2,
    ushort* __restrict__ Xhi, ushort* __restrict__ Xlo) {
  int t = blockIdx.x * 256 + threadIdx.x;
  if (t < 16384) {
    wsplit_one(W0, Whi0, Wlo0, 32, t);
  } else if (t < 81920) {
    wsplit_one(W1, Whi1, Wlo1, 128, t - 16384);
  } else if (t < 147456) {
    wsplit_one(W2, Whi2, Wlo2, 128, t - 81920);
  } else {
    x0split_one(x0, Xhi, Xlo, t - 147456);
  }
}

// One layer for one wave: o-tile = f*16..f*16+15, all d. h values come from
// h_src (LDS ping-pong buffer, or global x0 for layer 0 — resolved at compile
// time through inlining), relu output to LDS unless !WRITE_H.
template <int H, bool WRITE_H>
static __device__ __forceinline__ void run_layer(
    const float* __restrict__ h_src,   // [H*64] (LDS, or global for layer 0)
    float* __restrict__ h_next,        // [128*64] (LDS)
    const ushort* __restrict__ Whi, const ushort* __restrict__ Wlo,
    const float* __restrict__ bias, const float* __restrict__ lw,
    const bf16x8 (&xh)[4], const bf16x8 (&xl)[4],
    int f, int lane, float& score_part) {
  const int cid = lane & 15;
  const size_t hstride = (size_t)8 * 64 * 8;  // ushorts per hh
  const ushort* pwh = Whi + ((size_t)f * 64 + lane) * 8;
  const ushort* pwl = Wlo + ((size_t)f * 64 + lane) * 8;

  const f32x4 kZ = {0.f, 0.f, 0.f, 0.f};
  f32x4 acc[4];
#pragma unroll
  for (int fd = 0; fd < 4; ++fd) acc[fd] = kZ;

  // 3-deep A-fragment prefetch ring; 1-ahead h prefetch
  bf16x8 Ah[3], Al[3];
#pragma unroll
  for (int j = 0; j < 3; ++j) {
    Ah[j] = *reinterpret_cast<const bf16x8*>(pwh + (size_t)j * hstride);
    Al[j] = *reinterpret_cast<const bf16x8*>(pwl + (size_t)j * hstride);
  }
  float hvc[4];
#pragma unroll
  for (int fd = 0; fd < 4; ++fd) hvc[fd] = h_src[fd * 16 + cid];

#pragma unroll 1
  for (int hh3 = 0; hh3 < H; hh3 += 3) {  // H % 3 != 0: tail handled by clamp
#pragma unroll
    for (int j = 0; j < 3; ++j) {
      const int hh = hh3 + j;
      if (H % 3 != 0 && hh >= H) break;
      // h for hh+1 (clamped)
      const int hn1 = (hh + 1 < H) ? hh + 1 : H - 1;
      float nhv[4];
#pragma unroll
      for (int fd = 0; fd < 4; ++fd) nhv[fd] = h_src[hn1 * 64 + fd * 16 + cid];

      f32x4 y[4];
#pragma unroll
      for (int fd = 0; fd < 4; ++fd)
        y[fd] = __builtin_amdgcn_mfma_f32_16x16x32_bf16(Ah[j], xh[fd], kZ, 0, 0, 0);
#pragma unroll
      for (int fd = 0; fd < 4; ++fd)
        y[fd] = __builtin_amdgcn_mfma_f32_16x16x32_bf16(Ah[j], xl[fd], y[fd], 0, 0, 0);
#pragma unroll
      for (int fd = 0; fd < 4; ++fd)
        y[fd] = __builtin_amdgcn_mfma_f32_16x16x32_bf16(Al[j], xh[fd], y[fd], 0, 0, 0);

      // refill slot j with hh+3 (clamped) while MFMAs drain
      const int hn3 = (hh + 3 < H) ? hh + 3 : H - 1;
      Ah[j] = *reinterpret_cast<const bf16x8*>(pwh + (size_t)hn3 * hstride);
      Al[j] = *reinterpret_cast<const bf16x8*>(pwl + (size_t)hn3 * hstride);

#pragma unroll
      for (int fd = 0; fd < 4; ++fd)
#pragma unroll
        for (int r = 0; r < 4; ++r)
          acc[fd][r] = fmaf(hvc[fd], y[fd][r], acc[fd][r]);
#pragma unroll
      for (int fd = 0; fd < 4; ++fd) hvc[fd] = nhv[fd];
    }
  }

  // epilogue: bias + relu, write h_next (LDS), fold d-sum into score
  const int rg = lane >> 4;
#pragma unroll
  for (int r = 0; r < 4; ++r) {
    const int o = f * 16 + rg * 4 + r;
    const float bs = bias[o];
    float sd = 0.f;
#pragma unroll
    for (int fd = 0; fd < 4; ++fd) {
      float v = acc[fd][r] + bs;
      v = v > 0.f ? v : 0.f;
      if (WRITE_H) h_next[o * 64 + fd * 16 + cid] = v;
      sd += v;
    }
#pragma unroll
    for (int mk = 1; mk < 16; mk <<= 1) sd += __shfl_xor(sd, mk, 64);
    if (cid == 0) score_part = fmaf(sd, lw[o], score_part);
  }
}

__global__ __launch_bounds__(512, 2) void cin_fused_kernel(
    const float* __restrict__ x0,
    const ushort* __restrict__ Whi0, const ushort* __restrict__ Wlo0,
    const ushort* __restrict__ Whi1, const ushort* __restrict__ Wlo1,
    const ushort* __restrict__ Whi2, const ushort* __restrict__ Wlo2,
    const ushort* __restrict__ Xhi, const ushort* __restrict__ Xlo,
    const float* __restrict__ b0, const float* __restrict__ b1,
    const float* __restrict__ b2, const float* __restrict__ lw,
    const float* __restrict__ lb, float* __restrict__ out) {
  __shared__ float hA[Oo * Dd];  // 32 KB: layer-1 output
  __shared__ float hB[Oo * Dd];  // 32 KB: layer-0 output; [0..7] reused as sred
  // total LDS = exactly 65536 B -> 2 blocks fit a 128 KiB pool

  const int b = blockIdx.x;
  const int t = threadIdx.x;
  const int lane = t & 63;
  const int f = __builtin_amdgcn_readfirstlane(t >> 6);  // wave id = o-frag

  // x0 B-fragments, register-resident throughout
  bf16x8 xh[4], xl[4];
#pragma unroll
  for (int fd = 0; fd < 4; ++fd) {
    size_t off = (((size_t)b * 4 + fd) * 64 + lane) * 8;
    xh[fd] = *reinterpret_cast<const bf16x8*>(Xhi + off);
    xl[fd] = *reinterpret_cast<const bf16x8*>(Xlo + off);
  }

  float score_part = 0.f;
  // layer 0: h = x0[b] read directly from global (8 KB, L1-hot)
  run_layer<32, true>(x0 + (size_t)b * Mm * Dd, hB, Whi0, Wlo0, b0, lw,
                      xh, xl, f, lane, score_part);
  __syncthreads();
  run_layer<128, true>(hB, hA, Whi1, Wlo1, b1, lw + 128, xh, xl, f, lane, score_part);
  __syncthreads();
  run_layer<128, false>(hA, hB, Whi2, Wlo2, b2, lw + 256, xh, xl, f, lane, score_part);

  // block-wide score reduction (hB dead after layer-2 start)
#pragma unroll
  for (int mk = 1; mk < 64; mk <<= 1) score_part += __shfl_xor(score_part, mk, 64);
  if (lane == 0) hB[f] = score_part;
  __syncthreads();
  if (t == 0) {
    float tot = 0.f;
#pragma unroll
    for (int i = 0; i < 8; ++i) tot += hB[i];
    out[b] = tot + lb[0];
  }
}

extern "C" void kernel_launch(void* const* d_in, const int* in_sizes, int n_in,
                              void* d_out, int out_size, void* d_ws, size_t ws_size,
                              hipStream_t stream) {
  const float* x0 = (const float*)d_in[0];
  const float* W0 = (const float*)d_in[1];
  const float* b0 = (const float*)d_in[2];
  const float* W1 = (const float*)d_in[3];
  const float* b1 = (const float*)d_in[4];
  const float* W2 = (const float*)d_in[5];
  const float* b2 = (const float*)d_in[6];
  const float* lw = (const float*)d_in[7];
  const float* lb = (const float*)d_in[8];
  float* out = (float*)d_out;

  // workspace: only the split planes
  ushort* Whi0 = (ushort*)d_ws;
  ushort* Wlo0 = Whi0 + (size_t)32 * 8 * 64 * 8;
  ushort* Whi1 = Wlo0 + (size_t)32 * 8 * 64 * 8;
  ushort* Wlo1 = Whi1 + (size_t)128 * 8 * 64 * 8;
  ushort* Whi2 = Wlo1 + (size_t)128 * 8 * 64 * 8;
  ushort* Wlo2 = Whi2 + (size_t)128 * 8 * 64 * 8;
  ushort* Xhi = Wlo2 + (size_t)128 * 8 * 64 * 8;
  ushort* Xlo = Xhi + (size_t)Bb * 4 * 64 * 8;

  prep_kernel<<<dim3(1088), dim3(256), 0, stream>>>(W0, W1, W2, x0, Whi0, Wlo0,
                                                    Whi1, Wlo1, Whi2, Wlo2, Xhi, Xlo);

  cin_fused_kernel<<<dim3(Bb), dim3(512), 0, stream>>>(
      x0, Whi0, Wlo0, Whi1, Wlo1, Whi2, Wlo2, Xhi, Xlo, b0, b1, b2, lw, lb, out);
}